// Round 2
// baseline (217.585 us; speedup 1.0000x reference)
//
#include <hip/hip_runtime.h>
#include <hip/hip_bf16.h>

// GAT forward, MI355X. B=2,N=4096,F=256,O=64,H=4.
// k_h:   h = x@W (f32), w = h.a ; writes hT bf16 [B,H,O,N] + w f32 [B,H,N] to ws
// k_attn: flash-style softmax(leaky(w_i+w_j)+bias) @ h with bf16 MFMA PV.
//         Block = (b, 16-row i-tile), 16 waves = 4 heads x 4 j-quarters,
//         LDS combine of (m,l,acc) partials across quarters -> 8 waves/SIMD TLP.

constexpr int Bc = 2, Nc = 4096, Fc = 256, Oc = 64, Hc = 4;
constexpr float ALPHA = 0.2f;
constexpr float LOG2E = 1.4426950408889634f;

typedef __attribute__((ext_vector_type(8))) short bf16x8;
typedef __attribute__((ext_vector_type(4))) float f32x4;

static __device__ inline short f2bf(float x) {
    __hip_bfloat16 h = __float2bfloat16(x);
    return *reinterpret_cast<short*>(&h);
}

// ---------------- Kernel 1: per-head feature transform ----------------
// grid: B*H*(N/64) blocks, 256 threads. Thread computes 4n x 4o outputs.
__global__ __launch_bounds__(256) void k_h(const float* __restrict__ x,
                                           const float* __restrict__ W,
                                           const float* __restrict__ a,
                                           __hip_bfloat16* __restrict__ hT,
                                           float* __restrict__ wout) {
    __shared__ float xs[64][132];
    const int nb = Nc / 64;
    const int blk = blockIdx.x;
    const int nt = blk % nb;
    const int bh = blk / nb;
    const int h = bh % Hc;
    const int b = bh / Hc;
    const int tid = threadIdx.x;
    const int o_id = tid & 15, n_id = tid >> 4;
    const int o0 = o_id * 4, n0 = n_id * 4;

    float acc[4][4] = {};

    for (int fs = 0; fs < Fc; fs += 128) {
#pragma unroll
        for (int it = 0; it < 8; ++it) {
            int idx = it * 256 + tid;
            int r = idx >> 5, c = idx & 31;
            const float4 v = *reinterpret_cast<const float4*>(
                &x[((size_t)(b * Nc + nt * 64 + r)) * Fc + fs + c * 4]);
            *reinterpret_cast<float4*>(&xs[r][c * 4]) = v;
        }
        __syncthreads();
        for (int f = 0; f < 128; ++f) {
            const float4 wv = *reinterpret_cast<const float4*>(
                &W[((size_t)(h * Fc + fs + f)) * Oc + o0]);
            float xv[4];
#pragma unroll
            for (int r = 0; r < 4; ++r) xv[r] = xs[n0 + r][f];
#pragma unroll
            for (int r = 0; r < 4; ++r) {
                acc[r][0] = __builtin_fmaf(xv[r], wv.x, acc[r][0]);
                acc[r][1] = __builtin_fmaf(xv[r], wv.y, acc[r][1]);
                acc[r][2] = __builtin_fmaf(xv[r], wv.z, acc[r][2]);
                acc[r][3] = __builtin_fmaf(xv[r], wv.w, acc[r][3]);
            }
        }
        __syncthreads();
    }

    const float4 av = *reinterpret_cast<const float4*>(&a[h * Oc + o0]);
    float part[4];
#pragma unroll
    for (int r = 0; r < 4; ++r) {
        part[r] = acc[r][0] * av.x + acc[r][1] * av.y + acc[r][2] * av.z +
                  acc[r][3] * av.w;
#pragma unroll
        for (int off = 1; off < 16; off <<= 1)
            part[r] += __shfl_xor(part[r], off, 64);
    }
    const int n_glob = nt * 64 + n0;
    if (o_id == 0) {
#pragma unroll
        for (int r = 0; r < 4; ++r)
            wout[((size_t)(b * Hc + h)) * Nc + n_glob + r] = part[r];
    }
#pragma unroll
    for (int r = 0; r < 4; ++r)
#pragma unroll
        for (int c = 0; c < 4; ++c)
            hT[((size_t)(b * Hc + h) * Oc + o0 + c) * Nc + n_glob + r] =
                __float2bfloat16(acc[r][c]);
}

// ---------------- Kernel 2: fused attention ----------------
// grid: B*(N/16) blocks, 1024 threads = 16 waves.
// wave w: head hd=w&3, j-quarter q=w>>2 over [q*1024, q*1024+1024).
__global__ __launch_bounds__(1024, 8) void k_attn(
    const float* __restrict__ bias, const float* __restrict__ bvec,
    const float* __restrict__ wrow, const __hip_bfloat16* __restrict__ hT,
    float* __restrict__ out) {
    __shared__ float accs[16][16][64];  // 64 KB: per-wave raw PV accumulator
    __shared__ float ml[16][2][16];     // per-wave (m,l) per row
    const int blk = blockIdx.x;
    const int b = blk / (Nc / 16);
    const int i0 = (blk % (Nc / 16)) * 16;
    const int tid = threadIdx.x;
    const int w = tid >> 6;
    const int hd = w & 3;
    const int q = w >> 2;
    const int lane = tid & 63;
    const int li = lane & 15, lg = lane >> 4;

    const float wi = wrow[((size_t)(b * Hc + hd)) * Nc + i0 + li];
    const float* __restrict__ wj_base = &wrow[((size_t)(b * Hc + hd)) * Nc];
    const float* __restrict__ bias_row = &bias[((size_t)b * Nc + (i0 + li)) * Nc];
    const __hip_bfloat16* __restrict__ hTh = &hT[((size_t)(b * Hc + hd)) * Oc * Nc];

    f32x4 acc[4] = {{0.f, 0.f, 0.f, 0.f},
                    {0.f, 0.f, 0.f, 0.f},
                    {0.f, 0.f, 0.f, 0.f},
                    {0.f, 0.f, 0.f, 0.f}};
    float m_run = -1e30f, l_run = 0.f;

    const int jbeg = q * (Nc / 4), jend = jbeg + (Nc / 4);
    for (int j0 = jbeg; j0 < jend; j0 += 64) {
        float s[16];
#pragma unroll
        for (int sub = 0; sub < 2; ++sub) {
            const int jl = j0 + sub * 32 + lg * 8;
            const float4 bv0 = *reinterpret_cast<const float4*>(&bias_row[jl]);
            const float4 bv1 = *reinterpret_cast<const float4*>(&bias_row[jl + 4]);
            const float4 wj0 = *reinterpret_cast<const float4*>(&wj_base[jl]);
            const float4 wj1 = *reinterpret_cast<const float4*>(&wj_base[jl + 4]);
            const float vj[8] = {wj0.x, wj0.y, wj0.z, wj0.w,
                                 wj1.x, wj1.y, wj1.z, wj1.w};
            const float bb[8] = {bv0.x, bv0.y, bv0.z, bv0.w,
                                 bv1.x, bv1.y, bv1.z, bv1.w};
#pragma unroll
            for (int t = 0; t < 8; ++t) {
                const float v = wi + vj[t];
                const float lv = fmaxf(v, ALPHA * v);  // leaky_relu, alpha<1
                s[sub * 8 + t] = lv + bb[t];
            }
        }
        float mx = s[0];
#pragma unroll
        for (int t = 1; t < 16; ++t) mx = fmaxf(mx, s[t]);
        mx = fmaxf(mx, __shfl_xor(mx, 16, 64));
        mx = fmaxf(mx, __shfl_xor(mx, 32, 64));
        const float m_new = fmaxf(m_run, mx);
        const float scale = __builtin_amdgcn_exp2f((m_run - m_new) * LOG2E);
        const float mL = m_new * LOG2E;
        float p[16];
        float tsum = 0.f;
#pragma unroll
        for (int t = 0; t < 16; ++t) {
            p[t] = __builtin_amdgcn_exp2f(__builtin_fmaf(s[t], LOG2E, -mL));
            tsum += p[t];
        }
        tsum += __shfl_xor(tsum, 16, 64);
        tsum += __shfl_xor(tsum, 32, 64);
        l_run = l_run * scale + tsum;
        m_run = m_new;
        float sc[4];
#pragma unroll
        for (int r = 0; r < 4; ++r) sc[r] = __shfl(scale, lg * 4 + r, 64);
#pragma unroll
        for (int of = 0; of < 4; ++of) {
            acc[of][0] *= sc[0];
            acc[of][1] *= sc[1];
            acc[of][2] *= sc[2];
            acc[of][3] *= sc[3];
        }
        bf16x8 pa[2];
#pragma unroll
        for (int sub = 0; sub < 2; ++sub)
#pragma unroll
            for (int t = 0; t < 8; ++t) pa[sub][t] = f2bf(p[sub * 8 + t]);
#pragma unroll
        for (int of = 0; of < 4; ++of) {
#pragma unroll
            for (int sub = 0; sub < 2; ++sub) {
                const bf16x8 vb = *reinterpret_cast<const bf16x8*>(
                    &hTh[((size_t)(of * 16 + li)) * Nc + j0 + sub * 32 + lg * 8]);
                acc[of] = __builtin_amdgcn_mfma_f32_16x16x32_bf16(pa[sub], vb,
                                                                  acc[of], 0, 0, 0);
            }
        }
    }

    // stash raw partials (acc, m, l) to LDS
#pragma unroll
    for (int of = 0; of < 4; ++of)
#pragma unroll
        for (int r = 0; r < 4; ++r)
            accs[w][lg * 4 + r][of * 16 + li] = acc[of][r];
    if (lg == 0) {
        ml[w][0][li] = m_run;
        ml[w][1][li] = l_run;
    }
    __syncthreads();

    // combine across j-quarters per head, average heads. 1024 thr = 16x64 elems.
    const int row = tid >> 6, col = tid & 63;
    float osum = 0.f;
#pragma unroll
    for (int h = 0; h < 4; ++h) {
        float mq[4], lq[4];
#pragma unroll
        for (int qq = 0; qq < 4; ++qq) {
            mq[qq] = ml[qq * 4 + h][0][row];
            lq[qq] = ml[qq * 4 + h][1][row];
        }
        const float M = fmaxf(fmaxf(mq[0], mq[1]), fmaxf(mq[2], mq[3]));
        float l = 0.f, A = 0.f;
#pragma unroll
        for (int qq = 0; qq < 4; ++qq) {
            const float f = __builtin_amdgcn_exp2f((mq[qq] - M) * LOG2E);
            l = __builtin_fmaf(f, lq[qq], l);
            A = __builtin_fmaf(f, accs[qq * 4 + h][row][col], A);
        }
        osum += A / l;
    }
    const float bm = 0.25f * (bvec[col] + bvec[Oc + col] + bvec[2 * Oc + col] +
                              bvec[3 * Oc + col]);
    out[((size_t)(b * Nc + i0 + row)) * Oc + col] = 0.25f * osum + bm;
}

extern "C" void kernel_launch(void* const* d_in, const int* in_sizes, int n_in,
                              void* d_out, int out_size, void* d_ws, size_t ws_size,
                              hipStream_t stream) {
    const float* x = (const float*)d_in[0];     // [B,N,F]
    const float* bias = (const float*)d_in[1];  // [B,N,N]
    const float* W = (const float*)d_in[2];     // [H,F,O]
    const float* a = (const float*)d_in[3];     // [H,O]
    const float* bvec = (const float*)d_in[4];  // [H,O]
    float* out = (float*)d_out;                 // [B,N,O]

    __hip_bfloat16* hT = (__hip_bfloat16*)d_ws;  // B*H*O*N bf16 = 4 MB
    float* wbuf = (float*)((char*)d_ws + (size_t)Bc * Hc * Oc * Nc * 2);

    k_h<<<Bc * Hc * (Nc / 64), 256, 0, stream>>>(x, W, a, hT, wbuf);
    k_attn<<<Bc * (Nc / 16), 1024, 0, stream>>>(bias, bvec, wbuf, hT, out);
}

// Round 4
// 215.452 us; speedup vs baseline: 1.0099x; 1.0099x over previous
//
#include <hip/hip_runtime.h>
#include <hip/hip_bf16.h>

// GAT forward, MI355X. B=2,N=4096,F=256,O=64,H=4.
// k_h:   h = x@W (f32), w = h.a ; writes hT bf16 [B,H,O,N] + w f32 [B,H,N]
// k_attn: flash softmax(leaky(w_i+w_j)+bias) @ h with bf16 MFMA PV.
//         512 blocks x 16 waves (4 heads x 4 j-quarters), 16 tiles/wave.
//         R4 = R2 base + 128-VGPR budget + hoisted V-fragment loads +
//         1-deep bias register double-buffer. No macros/setprio/waitcnt.

constexpr int Bc = 2, Nc = 4096, Fc = 256, Oc = 64, Hc = 4;
constexpr float ALPHA = 0.2f;
constexpr float LOG2E = 1.4426950408889634f;

typedef __attribute__((ext_vector_type(8))) short bf16x8;
typedef __attribute__((ext_vector_type(4))) float f32x4;

static __device__ inline short f2bf(float x) {
    __hip_bfloat16 h = __float2bfloat16(x);
    return *reinterpret_cast<short*>(&h);
}

// ---------------- Kernel 1: per-head feature transform ----------------
// grid: B*H*(N/64) blocks, 256 threads. Thread computes 4n x 4o outputs.
__global__ __launch_bounds__(256) void k_h(const float* __restrict__ x,
                                           const float* __restrict__ W,
                                           const float* __restrict__ a,
                                           __hip_bfloat16* __restrict__ hT,
                                           float* __restrict__ wout) {
    __shared__ float xs[64][132];
    const int nb = Nc / 64;
    const int blk = blockIdx.x;
    const int nt = blk % nb;
    const int bh = blk / nb;
    const int h = bh % Hc;
    const int b = bh / Hc;
    const int tid = threadIdx.x;
    const int o_id = tid & 15, n_id = tid >> 4;
    const int o0 = o_id * 4, n0 = n_id * 4;

    float acc[4][4] = {};

    for (int fs = 0; fs < Fc; fs += 128) {
#pragma unroll
        for (int it = 0; it < 8; ++it) {
            int idx = it * 256 + tid;
            int r = idx >> 5, c = idx & 31;
            const float4 v = *reinterpret_cast<const float4*>(
                &x[((size_t)(b * Nc + nt * 64 + r)) * Fc + fs + c * 4]);
            *reinterpret_cast<float4*>(&xs[r][c * 4]) = v;
        }
        __syncthreads();
        for (int f = 0; f < 128; ++f) {
            const float4 wv = *reinterpret_cast<const float4*>(
                &W[((size_t)(h * Fc + fs + f)) * Oc + o0]);
            float xv[4];
#pragma unroll
            for (int r = 0; r < 4; ++r) xv[r] = xs[n0 + r][f];
#pragma unroll
            for (int r = 0; r < 4; ++r) {
                acc[r][0] = __builtin_fmaf(xv[r], wv.x, acc[r][0]);
                acc[r][1] = __builtin_fmaf(xv[r], wv.y, acc[r][1]);
                acc[r][2] = __builtin_fmaf(xv[r], wv.z, acc[r][2]);
                acc[r][3] = __builtin_fmaf(xv[r], wv.w, acc[r][3]);
            }
        }
        __syncthreads();
    }

    const float4 av = *reinterpret_cast<const float4*>(&a[h * Oc + o0]);
    float part[4];
#pragma unroll
    for (int r = 0; r < 4; ++r) {
        part[r] = acc[r][0] * av.x + acc[r][1] * av.y + acc[r][2] * av.z +
                  acc[r][3] * av.w;
#pragma unroll
        for (int off = 1; off < 16; off <<= 1)
            part[r] += __shfl_xor(part[r], off, 64);
    }
    const int n_glob = nt * 64 + n0;
    if (o_id == 0) {
#pragma unroll
        for (int r = 0; r < 4; ++r)
            wout[((size_t)(b * Hc + h)) * Nc + n_glob + r] = part[r];
    }
#pragma unroll
    for (int r = 0; r < 4; ++r)
#pragma unroll
        for (int c = 0; c < 4; ++c)
            hT[((size_t)(b * Hc + h) * Oc + o0 + c) * Nc + n_glob + r] =
                __float2bfloat16(acc[r][c]);
}

// ---------------- Kernel 2: fused attention ----------------
// grid: B*(N/16) blocks, 1024 threads = 16 waves = (head hd, quarter q).
__global__ __launch_bounds__(1024, 4) void k_attn(
    const float* __restrict__ bias, const float* __restrict__ bvec,
    const float* __restrict__ wrow, const __hip_bfloat16* __restrict__ hT,
    float* __restrict__ out) {
    __shared__ float accs[16][16][64];  // 64 KB
    __shared__ float ml[16][2][16];
    const int blk = blockIdx.x;
    const int b = blk / (Nc / 16);
    const int i0 = (blk % (Nc / 16)) * 16;
    const int tid = threadIdx.x;
    const int w = tid >> 6;
    const int hd = w & 3;
    const int q = w >> 2;
    const int lane = tid & 63;
    const int li = lane & 15, lg = lane >> 4;
    const int jl0 = lg * 8;

    const int jbeg = q * (Nc / 4), jend = jbeg + (Nc / 4);
    const float wi = wrow[((size_t)(b * Hc + hd)) * Nc + i0 + li];
    const float* __restrict__ wj_base = &wrow[((size_t)(b * Hc + hd)) * Nc];
    const float* __restrict__ bias_row = &bias[((size_t)b * Nc + (i0 + li)) * Nc];
    const __hip_bfloat16* __restrict__ hTh = &hT[((size_t)(b * Hc + hd)) * Oc * Nc];

    f32x4 acc[4] = {{0.f, 0.f, 0.f, 0.f},
                    {0.f, 0.f, 0.f, 0.f},
                    {0.f, 0.f, 0.f, 0.f},
                    {0.f, 0.f, 0.f, 0.f}};
    float m_run = -1e30f, l_run = 0.f;

    float4 bcur[4], bnxt[4];

    auto load_bias4 = [&](float4 (&D)[4], int J) {
        D[0] = *reinterpret_cast<const float4*>(&bias_row[J + jl0]);
        D[1] = *reinterpret_cast<const float4*>(&bias_row[J + jl0 + 4]);
        D[2] = *reinterpret_cast<const float4*>(&bias_row[J + 32 + jl0]);
        D[3] = *reinterpret_cast<const float4*>(&bias_row[J + 32 + jl0 + 4]);
    };

    auto tile = [&](float4 (&CB)[4], float4 (&NB)[4], int j0) {
        // prefetch next tile's bias (hidden under this tile's compute)
        if (j0 + 64 < jend) load_bias4(NB, j0 + 64);
        // hoist all 8 V-fragment loads (latency hides under softmax VALU)
        bf16x8 fr[8];
#pragma unroll
        for (int of = 0; of < 4; ++of)
#pragma unroll
            for (int sub = 0; sub < 2; ++sub)
                fr[of * 2 + sub] = *reinterpret_cast<const bf16x8*>(
                    &hTh[((size_t)(of * 16 + li)) * Nc + j0 + sub * 32 + lg * 8]);
        // scores s[16] for j = j0 + {0..7}+jl0 and j0+32+{0..7}+jl0
        float s[16];
#pragma unroll
        for (int u = 0; u < 4; ++u) {
            const int joff = j0 + ((u >> 1) ? 32 : 0) + jl0 + (u & 1) * 4;
            const float4 wv = *reinterpret_cast<const float4*>(&wj_base[joff]);
            const float4 bv = CB[u];
            float v;
            v = wi + wv.x; s[u * 4 + 0] = fmaxf(v, ALPHA * v) + bv.x;
            v = wi + wv.y; s[u * 4 + 1] = fmaxf(v, ALPHA * v) + bv.y;
            v = wi + wv.z; s[u * 4 + 2] = fmaxf(v, ALPHA * v) + bv.z;
            v = wi + wv.w; s[u * 4 + 3] = fmaxf(v, ALPHA * v) + bv.w;
        }
        // online softmax over this 64-wide tile (row li in lanes li+16k)
        float mx = s[0];
#pragma unroll
        for (int t = 1; t < 16; ++t) mx = fmaxf(mx, s[t]);
        mx = fmaxf(mx, __shfl_xor(mx, 16, 64));
        mx = fmaxf(mx, __shfl_xor(mx, 32, 64));
        const float m_new = fmaxf(m_run, mx);
        const float scale = __builtin_amdgcn_exp2f((m_run - m_new) * LOG2E);
        const float mL = m_new * LOG2E;
        float tsum = 0.f;
#pragma unroll
        for (int t = 0; t < 16; ++t) {
            s[t] = __builtin_amdgcn_exp2f(__builtin_fmaf(s[t], LOG2E, -mL));
            tsum += s[t];
        }
        tsum += __shfl_xor(tsum, 16, 64);
        tsum += __shfl_xor(tsum, 32, 64);
        l_run = l_run * scale + tsum;
        m_run = m_new;
        float sc[4];
#pragma unroll
        for (int r = 0; r < 4; ++r) sc[r] = __shfl(scale, lg * 4 + r, 64);
#pragma unroll
        for (int of = 0; of < 4; ++of) {
            acc[of][0] *= sc[0];
            acc[of][1] *= sc[1];
            acc[of][2] *= sc[2];
            acc[of][3] *= sc[3];
        }
        bf16x8 pa[2];
#pragma unroll
        for (int sub = 0; sub < 2; ++sub)
#pragma unroll
            for (int t = 0; t < 8; ++t) pa[sub][t] = f2bf(s[sub * 8 + t]);
#pragma unroll
        for (int of = 0; of < 4; ++of) {
            acc[of] = __builtin_amdgcn_mfma_f32_16x16x32_bf16(pa[0], fr[of * 2 + 0],
                                                              acc[of], 0, 0, 0);
            acc[of] = __builtin_amdgcn_mfma_f32_16x16x32_bf16(pa[1], fr[of * 2 + 1],
                                                              acc[of], 0, 0, 0);
        }
    };

    load_bias4(bcur, jbeg);
#pragma unroll 1
    for (int jp = 0; jp < 8; ++jp) {
        tile(bcur, bnxt, jbeg + jp * 128);
        tile(bnxt, bcur, jbeg + jp * 128 + 64);
    }

    // stash raw partials (acc, m, l) to LDS
#pragma unroll
    for (int of = 0; of < 4; ++of)
#pragma unroll
        for (int r = 0; r < 4; ++r)
            accs[w][lg * 4 + r][of * 16 + li] = acc[of][r];
    if (lg == 0) {
        ml[w][0][li] = m_run;
        ml[w][1][li] = l_run;
    }
    __syncthreads();

    // combine across j-quarters per head, average heads. 1024 thr = 16x64 elems.
    const int row = tid >> 6, col = tid & 63;
    float osum = 0.f;
#pragma unroll
    for (int h = 0; h < 4; ++h) {
        float mq[4], lq[4];
#pragma unroll
        for (int qq = 0; qq < 4; ++qq) {
            mq[qq] = ml[qq * 4 + h][0][row];
            lq[qq] = ml[qq * 4 + h][1][row];
        }
        const float M = fmaxf(fmaxf(mq[0], mq[1]), fmaxf(mq[2], mq[3]));
        float l = 0.f, A = 0.f;
#pragma unroll
        for (int qq = 0; qq < 4; ++qq) {
            const float f = __builtin_amdgcn_exp2f((mq[qq] - M) * LOG2E);
            l = __builtin_fmaf(f, lq[qq], l);
            A = __builtin_fmaf(f, accs[qq * 4 + h][row][col], A);
        }
        osum += A / l;
    }
    const float bm = 0.25f * (bvec[col] + bvec[Oc + col] + bvec[2 * Oc + col] +
                              bvec[3 * Oc + col]);
    out[((size_t)(b * Nc + i0 + row)) * Oc + col] = 0.25f * osum + bm;
}

extern "C" void kernel_launch(void* const* d_in, const int* in_sizes, int n_in,
                              void* d_out, int out_size, void* d_ws, size_t ws_size,
                              hipStream_t stream) {
    const float* x = (const float*)d_in[0];     // [B,N,F]
    const float* bias = (const float*)d_in[1];  // [B,N,N]
    const float* W = (const float*)d_in[2];     // [H,F,O]
    const float* a = (const float*)d_in[3];     // [H,O]
    const float* bvec = (const float*)d_in[4];  // [H,O]
    float* out = (float*)d_out;                 // [B,N,O]

    __hip_bfloat16* hT = (__hip_bfloat16*)d_ws;  // B*H*O*N bf16 = 4 MB
    float* wbuf = (float*)((char*)d_ws + (size_t)Bc * Hc * Oc * Nc * 2);

    k_h<<<Bc * Hc * (Nc / 64), 256, 0, stream>>>(x, W, a, hT, wbuf);
    k_attn<<<Bc * (Nc / 16), 1024, 0, stream>>>(bias, bvec, wbuf, hT, out);
}

// Round 5
// 106.452 us; speedup vs baseline: 2.0440x; 2.0239x over previous
//
#include <hip/hip_runtime.h>
#include <hip/hip_bf16.h>

// GAT forward, MI355X. B=2,N=4096,F=256,O=64,H=4.
// k_h:   h = x@W (f32), w = h.a ; writes hTB (bf16, MFMA fragment-contiguous) + w f32
// k_attn: flash softmax(leaky(w_i+w_j)+bias) @ h with bf16 MFMA PV.
//   512 blocks x 16 waves = (head hd, j-chunk c4); j-supertiles of 256.
//   Bias tile [16][256] staged in LDS once per supertile, shared by all heads
//   (stride-257 overlay in accs region, double-buffered, T14 split-stage).
//   V-fragments loaded contiguously from hTB (lane*16B). Epilogue as R2/R4.

constexpr int Bc = 2, Nc = 4096, Fc = 256, Oc = 64, Hc = 4;
constexpr float ALPHA = 0.2f;
constexpr float LOG2E = 1.4426950408889634f;

typedef __attribute__((ext_vector_type(8))) short bf16x8;
typedef __attribute__((ext_vector_type(4))) float f32x4;

static __device__ inline short f2bf(float x) {
    __hip_bfloat16 h = __float2bfloat16(x);
    return *reinterpret_cast<short*>(&h);
}

// offset (in shorts) of fragment element inside one (b,h) plane of hTB.
// k = of*2+sub ; lane = lg*16+li ; element t <-> (o = of*16+li, j = jt*64+sub*32+lg*8+t)
static __device__ inline int frag_off(int jt, int k, int lane, int t) {
    return jt * 4096 + k * 512 + lane * 8 + t;
}

// ---------------- Kernel 1: per-head feature transform ----------------
// grid: B*H*(N/64) blocks, 256 threads. Thread computes 4n x 4o outputs.
__global__ __launch_bounds__(256) void k_h(const float* __restrict__ x,
                                           const float* __restrict__ W,
                                           const float* __restrict__ a,
                                           short* __restrict__ hTB,
                                           float* __restrict__ wout) {
    __shared__ float xs[64][132];
    const int nb = Nc / 64;
    const int blk = blockIdx.x;
    const int nt = blk % nb;
    const int bh = blk / nb;
    const int h = bh % Hc;
    const int b = bh / Hc;
    const int tid = threadIdx.x;
    const int o_id = tid & 15, n_id = tid >> 4;
    const int o0 = o_id * 4, n0 = n_id * 4;

    float acc[4][4] = {};

    for (int fs = 0; fs < Fc; fs += 128) {
#pragma unroll
        for (int it = 0; it < 8; ++it) {
            int idx = it * 256 + tid;
            int r = idx >> 5, c = idx & 31;
            const float4 v = *reinterpret_cast<const float4*>(
                &x[((size_t)(b * Nc + nt * 64 + r)) * Fc + fs + c * 4]);
            *reinterpret_cast<float4*>(&xs[r][c * 4]) = v;
        }
        __syncthreads();
        for (int f = 0; f < 128; ++f) {
            const float4 wv = *reinterpret_cast<const float4*>(
                &W[((size_t)(h * Fc + fs + f)) * Oc + o0]);
            float xv[4];
#pragma unroll
            for (int r = 0; r < 4; ++r) xv[r] = xs[n0 + r][f];
#pragma unroll
            for (int r = 0; r < 4; ++r) {
                acc[r][0] = __builtin_fmaf(xv[r], wv.x, acc[r][0]);
                acc[r][1] = __builtin_fmaf(xv[r], wv.y, acc[r][1]);
                acc[r][2] = __builtin_fmaf(xv[r], wv.z, acc[r][2]);
                acc[r][3] = __builtin_fmaf(xv[r], wv.w, acc[r][3]);
            }
        }
        __syncthreads();
    }

    const float4 av = *reinterpret_cast<const float4*>(&a[h * Oc + o0]);
    float part[4];
#pragma unroll
    for (int r = 0; r < 4; ++r) {
        part[r] = acc[r][0] * av.x + acc[r][1] * av.y + acc[r][2] * av.z +
                  acc[r][3] * av.w;
#pragma unroll
        for (int off = 1; off < 16; off <<= 1)
            part[r] += __shfl_xor(part[r], off, 64);
    }
    const int n_glob = nt * 64 + n0;
    if (o_id == 0) {
#pragma unroll
        for (int r = 0; r < 4; ++r)
            wout[((size_t)(b * Hc + h)) * Nc + n_glob + r] = part[r];
    }
    // fragment-layout write. n_local = n0+r -> sub,lg,t0+r ; o = o0+c -> of,li
    const int sub = n0 >> 5;
    const int lg = (n0 >> 3) & 3;
    const int t0 = n0 & 7;  // {0,4}: 8B-aligned short4 in t
    short* base = hTB + ((size_t)(b * Hc + h)) * (Nc * Oc);
#pragma unroll
    for (int c = 0; c < 4; ++c) {
        const int o = o0 + c;
        const int of = o >> 4, li = o & 15;
        short4 v;
        v.x = f2bf(acc[0][c]);
        v.y = f2bf(acc[1][c]);
        v.z = f2bf(acc[2][c]);
        v.w = f2bf(acc[3][c]);
        *reinterpret_cast<short4*>(&base[frag_off(nt, of * 2 + sub, lg * 16 + li, t0)]) = v;
    }
}

// ---------------- Kernel 2: fused attention ----------------
// grid: B*(N/16) blocks, 1024 threads = 16 waves = (head hd = w&3, chunk c4 = w>>2).
__global__ __launch_bounds__(1024, 4) void k_attn(
    const float* __restrict__ bias, const float* __restrict__ bvec,
    const float* __restrict__ wrow, const short* __restrict__ hTB,
    float* __restrict__ out) {
    __shared__ float accs[16][16][64];  // 64 KB; first 8224 floats = bias stage overlay
    __shared__ float ml[16][2][16];
    float* bias_sm = &accs[0][0][0];  // [2][16][257] doubles-buffered bias tile

    const int blk = blockIdx.x;
    const int b = blk / (Nc / 16);
    const int i0 = (blk % (Nc / 16)) * 16;
    const int tid = threadIdx.x;
    const int w = tid >> 6;
    const int hd = w & 3;
    const int c4 = w >> 2;
    const int lane = tid & 63;
    const int li = lane & 15, lg = lane >> 4;
    const int jl0 = lg * 8;

    const float wi = wrow[((size_t)(b * Hc + hd)) * Nc + i0 + li];
    const float* __restrict__ wj_base = &wrow[((size_t)(b * Hc + hd)) * Nc];
    const short* __restrict__ fb =
        hTB + ((size_t)(b * Hc + hd)) * (Nc * Oc) + lane * 8;

    // bias staging: thread covers row w, cols (tid&63) + 64k of the 256-wide tile
    const int scol = tid & 63;
    const float* __restrict__ stage_src =
        &bias[((size_t)(b * Nc + i0 + w)) * Nc + scol];
    float* stage_dst = bias_sm + w * 257 + scol;  // +buf*4112 +64k

    f32x4 acc[4] = {{0.f, 0.f, 0.f, 0.f},
                    {0.f, 0.f, 0.f, 0.f},
                    {0.f, 0.f, 0.f, 0.f},
                    {0.f, 0.f, 0.f, 0.f}};
    float m_run = -1e30f, l_run = 0.f;

    // prologue: stage supertile 0 into buf 0
    float pre[4];
#pragma unroll
    for (int k2 = 0; k2 < 4; ++k2) pre[k2] = stage_src[64 * k2];
#pragma unroll
    for (int k2 = 0; k2 < 4; ++k2) stage_dst[64 * k2] = pre[k2];
    __syncthreads();

    int buf = 0;
#pragma unroll 1
    for (int st = 0; st < 16; ++st) {
        // T14 early: issue next supertile's global bias loads
        if (st < 15) {
#pragma unroll
            for (int k2 = 0; k2 < 4; ++k2)
                pre[k2] = stage_src[(size_t)(st + 1) * 256 + 64 * k2];
        }
        // ---- compute this wave's 64-j chunk: j0 = st*256 + c4*64
        const int jt = st * 4 + c4;
        bf16x8 fr[8];
#pragma unroll
        for (int k = 0; k < 8; ++k)
            fr[k] = *reinterpret_cast<const bf16x8*>(fb + jt * 4096 + k * 512);
        // bias from LDS (stride-257: 2-way banks = free)
        const float* bsm = bias_sm + buf * 4112 + li * 257 + c4 * 64 + jl0;
        float s[16];
#pragma unroll
        for (int t = 0; t < 8; ++t) {
            s[t] = bsm[t];
            s[8 + t] = bsm[32 + t];
        }
        // wj (16-lane broadcast loads) + leaky(wi+wj)
        const int j0 = st * 256 + c4 * 64;
#pragma unroll
        for (int u = 0; u < 4; ++u) {
            const float4 wv = *reinterpret_cast<const float4*>(
                &wj_base[j0 + (u >> 1) * 32 + jl0 + (u & 1) * 4]);
            float v;
            v = wi + wv.x; s[u * 4 + 0] += fmaxf(v, ALPHA * v);
            v = wi + wv.y; s[u * 4 + 1] += fmaxf(v, ALPHA * v);
            v = wi + wv.z; s[u * 4 + 2] += fmaxf(v, ALPHA * v);
            v = wi + wv.w; s[u * 4 + 3] += fmaxf(v, ALPHA * v);
        }
        // online softmax across this 64-wide tile (row li in lanes li+16k)
        float mx = s[0];
#pragma unroll
        for (int t = 1; t < 16; ++t) mx = fmaxf(mx, s[t]);
        mx = fmaxf(mx, __shfl_xor(mx, 16, 64));
        mx = fmaxf(mx, __shfl_xor(mx, 32, 64));
        const float m_new = fmaxf(m_run, mx);
        const float scale = __builtin_amdgcn_exp2f((m_run - m_new) * LOG2E);
        const float mL = m_new * LOG2E;
        float tsum = 0.f;
#pragma unroll
        for (int t = 0; t < 16; ++t) {
            s[t] = __builtin_amdgcn_exp2f(__builtin_fmaf(s[t], LOG2E, -mL));
            tsum += s[t];
        }
        tsum += __shfl_xor(tsum, 16, 64);
        tsum += __shfl_xor(tsum, 32, 64);
        l_run = l_run * scale + tsum;
        m_run = m_new;
        float sc[4];
#pragma unroll
        for (int r = 0; r < 4; ++r) sc[r] = __shfl(scale, lg * 4 + r, 64);
#pragma unroll
        for (int of = 0; of < 4; ++of) {
            acc[of][0] *= sc[0];
            acc[of][1] *= sc[1];
            acc[of][2] *= sc[2];
            acc[of][3] *= sc[3];
        }
        bf16x8 pa[2];
#pragma unroll
        for (int sub = 0; sub < 2; ++sub)
#pragma unroll
            for (int t = 0; t < 8; ++t) pa[sub][t] = f2bf(s[sub * 8 + t]);
        __builtin_amdgcn_s_setprio(1);
#pragma unroll
        for (int of = 0; of < 4; ++of) {
            acc[of] = __builtin_amdgcn_mfma_f32_16x16x32_bf16(pa[0], fr[of * 2 + 0],
                                                              acc[of], 0, 0, 0);
            acc[of] = __builtin_amdgcn_mfma_f32_16x16x32_bf16(pa[1], fr[of * 2 + 1],
                                                              acc[of], 0, 0, 0);
        }
        __builtin_amdgcn_s_setprio(0);
        // T14 late: commit next supertile's bias to the other buffer
        if (st < 15) {
#pragma unroll
            for (int k2 = 0; k2 < 4; ++k2)
                stage_dst[(buf ^ 1) * 4112 + 64 * k2] = pre[k2];
        }
        __syncthreads();
        buf ^= 1;
    }

    // stash raw partials (acc, m, l); bias overlay no longer needed (post-barrier)
#pragma unroll
    for (int of = 0; of < 4; ++of)
#pragma unroll
        for (int r = 0; r < 4; ++r)
            accs[w][lg * 4 + r][of * 16 + li] = acc[of][r];
    if (lg == 0) {
        ml[w][0][li] = m_run;
        ml[w][1][li] = l_run;
    }
    __syncthreads();

    // combine across j-chunks per head, average heads. 1024 thr = 16x64 elems.
    const int row = tid >> 6, col = tid & 63;
    float osum = 0.f;
#pragma unroll
    for (int h = 0; h < 4; ++h) {
        float mq[4], lq[4];
#pragma unroll
        for (int qq = 0; qq < 4; ++qq) {
            mq[qq] = ml[qq * 4 + h][0][row];
            lq[qq] = ml[qq * 4 + h][1][row];
        }
        const float M = fmaxf(fmaxf(mq[0], mq[1]), fmaxf(mq[2], mq[3]));
        float l = 0.f, A = 0.f;
#pragma unroll
        for (int qq = 0; qq < 4; ++qq) {
            const float f = __builtin_amdgcn_exp2f((mq[qq] - M) * LOG2E);
            l = __builtin_fmaf(f, lq[qq], l);
            A = __builtin_fmaf(f, accs[qq * 4 + h][row][col], A);
        }
        osum += A / l;
    }
    const float bm = 0.25f * (bvec[col] + bvec[Oc + col] + bvec[2 * Oc + col] +
                              bvec[3 * Oc + col]);
    out[((size_t)(b * Nc + i0 + row)) * Oc + col] = 0.25f * osum + bm;
}

extern "C" void kernel_launch(void* const* d_in, const int* in_sizes, int n_in,
                              void* d_out, int out_size, void* d_ws, size_t ws_size,
                              hipStream_t stream) {
    const float* x = (const float*)d_in[0];     // [B,N,F]
    const float* bias = (const float*)d_in[1];  // [B,N,N]
    const float* W = (const float*)d_in[2];     // [H,F,O]
    const float* a = (const float*)d_in[3];     // [H,O]
    const float* bvec = (const float*)d_in[4];  // [H,O]
    float* out = (float*)d_out;                 // [B,N,O]

    short* hTB = (short*)d_ws;  // B*H*N*O bf16 = 4 MB, fragment layout
    float* wbuf = (float*)((char*)d_ws + (size_t)Bc * Hc * Oc * Nc * 2);

    k_h<<<Bc * Hc * (Nc / 64), 256, 0, stream>>>(x, W, a, hTB, wbuf);
    k_attn<<<Bc * (Nc / 16), 1024, 0, stream>>>(bias, bvec, wbuf, hTB, out);
}